// Round 5
// baseline (1154.371 us; speedup 1.0000x reference)
//
#include <hip/hip_runtime.h>
#include <math.h>

constexpr int N = 20000, E = 160000, Bb = 1000;
constexpr int DIN = 7, HID = 64, HEADS = 4, CTXD = 3, EDIM = 5, NL = 4;
constexpr int HH = HEADS * HID; // 256

__device__ __forceinline__ float wredsum(float v) {
#pragma unroll
  for (int o = 32; o; o >>= 1) v += __shfl_xor(v, o, 64);
  return v;
}

__device__ __forceinline__ float wredmax(float v) {
#pragma unroll
  for (int o = 32; o; o >>= 1) v = fmaxf(v, __shfl_xor(v, o, 64));
  return v;
}

// node init with ctx MLP fused in (3 FMAs per thread, saves a kernel+buffer)
__global__ void k_node_init(const float* __restrict__ x, const float* __restrict__ emb_W,
                            const float* __restrict__ emb_b, const int* __restrict__ role,
                            const float* __restrict__ role_tab, const int* __restrict__ side,
                            const float* __restrict__ side_tab, const float* __restrict__ frame_t,
                            const float* __restrict__ temp_tab, const int* __restrict__ batch,
                            const float* __restrict__ ctx, const float* __restrict__ ctx_W,
                            const float* __restrict__ ctx_b, const float* __restrict__ form_tab,
                            const float* __restrict__ align_tab, const int* __restrict__ form,
                            const int* __restrict__ alig, float* __restrict__ h) {
  int t = blockIdx.x * blockDim.x + threadIdx.x;
  if (t >= N * HID) return;
  int n = t >> 6, j = t & 63;
  float a = emb_b[j];
#pragma unroll
  for (int k = 0; k < DIN; ++k) a += x[n * DIN + k] * emb_W[k * HID + j];
  a = fmaxf(a, 0.f);
  a += role_tab[role[n] * HID + j];
  if (j < 32) a += side_tab[side[n] * 32 + j];
  int ti = (int)(frame_t[0] * 99.f);
  ti = ti < 0 ? 0 : (ti > 99 ? 99 : ti);
  a += temp_tab[ti * HID + j];
  int b = batch[n];
  float c = ctx_b[j];
#pragma unroll
  for (int k = 0; k < CTXD; ++k) c += ctx[b * CTXD + k] * ctx_W[k * HID + j];
  c = fmaxf(c, 0.f);
  c += form_tab[form[b] * HID + j] + align_tab[alig[b] * HID + j];
  h[t] = a + c;
}

__global__ void k_count(const int* __restrict__ ei, int* __restrict__ deg_dst,
                        int* __restrict__ deg_src) {
  int e = blockIdx.x * blockDim.x + threadIdx.x;
  if (e >= E) return;
  atomicAdd(&deg_src[ei[e]], 1);
  atomicAdd(&deg_dst[ei[E + e]], 1);
}

// W2g = W2 @ Wg ; bg2 = bg + b2 @ Wg   (lets k_edge compute gate from pre directly)
__global__ void k_fuse(const float* __restrict__ W2, const float* __restrict__ Wg,
                       const float* __restrict__ b2, const float* __restrict__ bg,
                       float* __restrict__ W2g, float* __restrict__ bg2) {
  int t = blockIdx.x * 256 + threadIdx.x;
  if (t < HID * HID) {
    int i = t >> 6, j = t & 63;
    float a = 0.f;
#pragma unroll
    for (int k = 0; k < HID; ++k) a += W2[i * HID + k] * Wg[k * HID + j];
    W2g[t] = a;
  }
  if (t < HID) {
    float a = bg[t];
#pragma unroll
    for (int k = 0; k < HID; ++k) a += b2[k] * Wg[k * HID + t];
    bg2[t] = a;
  }
}

// both exclusive scans in one launch; shfl wave-scan + cross-wave LDS
__global__ void k_scan2(const int* __restrict__ degA, int* __restrict__ rowA,
                        int* __restrict__ curA, const int* __restrict__ degB,
                        int* __restrict__ rowB, int* __restrict__ curB, int n) {
  __shared__ int wsum[16];
  __shared__ int carry;
  int t = threadIdx.x, wid = t >> 6, lane = t & 63;
  for (int pass = 0; pass < 2; ++pass) {
    const int* deg = pass ? degB : degA;
    int* row = pass ? rowB : rowA;
    int* cur = pass ? curB : curA;
    if (t == 0) carry = 0;
    __syncthreads();
    for (int base = 0; base < n; base += 1024) {
      int v = (base + t < n) ? deg[base + t] : 0;
      int s = v;
#pragma unroll
      for (int off = 1; off < 64; off <<= 1) {
        int x = __shfl_up(s, off, 64);
        if (lane >= off) s += x;
      }
      if (lane == 63) wsum[wid] = s;
      __syncthreads();
      if (wid == 0) {
        int ws = (lane < 16) ? wsum[lane] : 0;
#pragma unroll
        for (int off = 1; off < 16; off <<= 1) {
          int x = __shfl_up(ws, off, 64);
          if (lane >= off) ws += x;
        }
        if (lane < 16) wsum[lane] = ws;
      }
      __syncthreads();
      int wexcl = (wid == 0) ? 0 : wsum[wid - 1];
      int r = carry + wexcl + (s - v);
      if (base + t < n) {
        row[base + t] = r;
        cur[base + t] = r;
      }
      __syncthreads();
      if (t == 0) carry += wsum[15];
      __syncthreads();
    }
  }
}

__global__ void k_scatter(const int* __restrict__ ei, int* __restrict__ cur_dst,
                          int* __restrict__ cur_src, int* __restrict__ eid_dst,
                          int* __restrict__ esrc_dst, int* __restrict__ esrc_srt,
                          int* __restrict__ edst_srt) {
  int e = blockIdx.x * blockDim.x + threadIdx.x;
  if (e >= E) return;
  int s = ei[e], d = ei[E + e];
  int ps = atomicAdd(&cur_src[s], 1);
  esrc_srt[ps] = s;
  edst_srt[ps] = d;
  int pd = atomicAdd(&cur_dst[d], 1);
  eid_dst[pd] = e;
  esrc_dst[pd] = s;
}

__global__ void k_loop_attr(const int* __restrict__ row_dst, const int* __restrict__ deg_dst,
                            const int* __restrict__ eid_dst, const float* __restrict__ ea,
                            float* __restrict__ la) {
  int n = blockIdx.x * blockDim.x + threadIdx.x;
  if (n >= N) return;
  int beg = row_dst[n], cnt = deg_dst[n];
  float s[EDIM] = {0.f, 0.f, 0.f, 0.f, 0.f};
  for (int j = 0; j < cnt; ++j) {
    int e = eid_dst[beg + j];
#pragma unroll
    for (int k = 0; k < EDIM; ++k) s[k] += ea[(size_t)e * EDIM + k];
  }
  float inv = 1.f / fmaxf((float)cnt, 1.f);
#pragma unroll
  for (int k = 0; k < EDIM; ++k) la[n * EDIM + k] = s[k] * inv;
}

__global__ __launch_bounds__(256) void k_xlxr(const float* __restrict__ h,
                                              const float* __restrict__ Wl,
                                              const float* __restrict__ bl,
                                              const float* __restrict__ Wr,
                                              const float* __restrict__ br,
                                              float* __restrict__ xl, float* __restrict__ xr) {
  constexpr int NB = 16;
  __shared__ float hs[NB][HID];
  int n0 = blockIdx.x * NB;
  for (int idx = threadIdx.x; idx < NB * HID; idx += 256) {
    int r = idx >> 6, c = idx & 63;
    int n = n0 + r;
    hs[r][c] = (n < N) ? h[n * HID + c] : 0.f;
  }
  __syncthreads();
  int t = threadIdx.x;
  float wl[HID], wr[HID];
#pragma unroll
  for (int k = 0; k < HID; ++k) {
    wl[k] = Wl[k * HH + t];
    wr[k] = Wr[k * HH + t];
  }
  float blv = bl[t], brv = br[t];
  for (int r = 0; r < NB; ++r) {
    int n = n0 + r;
    if (n >= N) break;
    float al = blv, ar = brv;
#pragma unroll
    for (int k = 0; k < HID; ++k) {
      float hv = hs[r][k];
      al += hv * wl[k];
      ar += hv * wr[k];
    }
    xl[(size_t)n * HH + t] = al;
    xr[(size_t)n * HH + t] = ar;
  }
}

// per-node GATv2. Logit phase: 16-lane groups, 4 edges/wave/iter, float4 cols,
// 4-step group reduce -> LDS. Then wave max/exp/sum, then pure-FMA accumulate.
__global__ __launch_bounds__(256) void k_gat(
    const float* __restrict__ xl, const float* __restrict__ xr, const float* __restrict__ ea,
    const float* __restrict__ la, const int* __restrict__ row_dst,
    const int* __restrict__ deg_dst, const int* __restrict__ eid_dst,
    const int* __restrict__ esrc_dst, const float* __restrict__ We,
    const float* __restrict__ att, const float* __restrict__ biasL,
    const float* __restrict__ lng, const float* __restrict__ lnb, float* __restrict__ h) {
  int n = blockIdx.x;
  int w = threadIdx.x >> 6, lane = threadIdx.x & 63;
  int col = w * HID + lane;
  int g = lane >> 4, q = lane & 15, c4 = q * 4;
  const float* base = xr + (size_t)n * HH + w * HID + c4;
  float4 xr4 = *(const float4*)base;
  float4 att4 = *(const float4*)(att + w * HID + c4);
  float4 we4[EDIM];
#pragma unroll
  for (int k = 0; k < EDIM; ++k) we4[k] = *(const float4*)(We + k * HH + w * HID + c4);
  int beg = row_dst[n], cnt = deg_dst[n];
  int tot = cnt + 1;  // + self loop (idx 0)
  int ncache = cnt < 63 ? cnt : 63;
  int srcn_c = (lane < ncache) ? esrc_dst[beg + lane] : 0;
  int eid_c = (lane < ncache) ? eid_dst[beg + lane] : 0;
  int nf = tot < 64 ? tot : 64;
  __shared__ float lgs[HEADS][64];
  for (int j = 0; j * 4 < nf; ++j) {
    int idx = j * 4 + g;
    float dot = 0.f;
    if (idx < nf) {
      int srcn = (idx == 0) ? n : __shfl(srcn_c, idx - 1, 64);
      const float* eap;
      if (idx == 0) {
        eap = la + (size_t)n * EDIM;
      } else {
        int e = __shfl(eid_c, idx - 1, 64);
        eap = ea + (size_t)e * EDIM;
      }
      float4 ep;
      ep.x = ep.y = ep.z = ep.w = 0.f;
#pragma unroll
      for (int k = 0; k < EDIM; ++k) {
        float ev = eap[k];
        ep.x += ev * we4[k].x;
        ep.y += ev * we4[k].y;
        ep.z += ev * we4[k].z;
        ep.w += ev * we4[k].w;
      }
      float4 xl4 = *(const float4*)(xl + (size_t)srcn * HH + w * HID + c4);
      float v0 = xl4.x + xr4.x + ep.x;
      float v1 = xl4.y + xr4.y + ep.y;
      float v2 = xl4.z + xr4.z + ep.z;
      float v3 = xl4.w + xr4.w + ep.w;
      v0 = v0 > 0.f ? v0 : 0.2f * v0;
      v1 = v1 > 0.f ? v1 : 0.2f * v1;
      v2 = v2 > 0.f ? v2 : 0.2f * v2;
      v3 = v3 > 0.f ? v3 : 0.2f * v3;
      dot = v0 * att4.x + v1 * att4.y + v2 * att4.z + v3 * att4.w;
    }
#pragma unroll
    for (int o = 1; o < 16; o <<= 1) dot += __shfl_xor(dot, o, 64);
    if (q == 0 && idx < nf) lgs[w][idx] = dot;
  }
  float mylg = (lane < nf) ? lgs[w][lane] : -INFINITY;
  float m = wredmax(mylg);
  float p = (lane < nf) ? __expf(mylg - m) : 0.f;
  float s = wredsum(p);
  float acc = 0.f;
  for (int idx = 0; idx < nf; ++idx) {
    int srcn = (idx == 0) ? n : __shfl(srcn_c, idx - 1, 64);
    float pi = __shfl(p, idx, 64);
    acc += pi * xl[(size_t)srcn * HH + col];
  }
  // overflow (deg > 63), rare: online merge with lazily-loaded scalar We col
  if (tot > 64) {
    float wes[EDIM];
#pragma unroll
    for (int k = 0; k < EDIM; ++k) wes[k] = We[k * HH + col];
    float xrs = xr[(size_t)n * HH + col];
    float attws = att[col];
    for (int idx = 64; idx < tot; ++idx) {
      int pos = beg + idx - 1;
      int srcn = esrc_dst[pos];
      int e = eid_dst[pos];
      const float* eap = ea + (size_t)e * EDIM;
      float ep = 0.f;
#pragma unroll
      for (int k = 0; k < EDIM; ++k) ep += eap[k] * wes[k];
      float xls = xl[(size_t)srcn * HH + col];
      float v = xls + xrs + ep;
      v = v > 0.f ? v : 0.2f * v;
      float lg = wredsum(v * attws);
      float nm = fmaxf(m, lg);
      float sc = __expf(m - nm), pp = __expf(lg - nm);
      s = s * sc + pp;
      acc = acc * sc + pp * xls;
      m = nm;
    }
  }
  float outv = acc / (s + 1e-16f);
  __shared__ float heads[HEADS][HID];
  heads[w][lane] = outv;
  __syncthreads();
  if (w == 0) {
    float hv = (heads[0][lane] + heads[1][lane] + heads[2][lane] + heads[3][lane]) * 0.25f +
               biasL[lane];
    hv = fmaxf(hv, 0.f);
    float v = hv + h[n * HID + lane];
    float mu = wredsum(v) * (1.f / 64.f);
    float d = v - mu;
    float var = wredsum(d * d) * (1.f / 64.f);
    h[n * HID + lane] = d * rsqrtf(var + 1e-5f) * lng[lane] + lnb[lane];
  }
}

__global__ __launch_bounds__(256) void k_uv(const float* __restrict__ h,
                                            const float* __restrict__ W1,
                                            const float* __restrict__ b1,
                                            float* __restrict__ u, float* __restrict__ v) {
  constexpr int NB = 16;
  __shared__ float hs[NB][HID];
  int n0 = blockIdx.x * NB;
  for (int idx = threadIdx.x; idx < NB * HID; idx += 256) {
    int r = idx >> 6, c = idx & 63;
    int n = n0 + r;
    hs[r][c] = (n < N) ? h[n * HID + c] : 0.f;
  }
  __syncthreads();
  int j = threadIdx.x & 63, q = threadIdx.x >> 6;
  float wa[HID], wb[HID];
#pragma unroll
  for (int k = 0; k < HID; ++k) {
    wa[k] = W1[k * HID + j];
    wb[k] = W1[(HID + k) * HID + j];
  }
  float b1v = b1[j];
  for (int r = q; r < NB; r += 4) {
    int n = n0 + r;
    if (n >= N) continue;
    float au = b1v, av = 0.f;
#pragma unroll
    for (int k = 0; k < HID; ++k) {
      float hv = hs[r][k];
      au += hv * wa[k];
      av += hv * wb[k];
    }
    u[(size_t)n * HID + j] = au;
    v[(size_t)n * HID + j] = av;
  }
}

// 256-thr blocks, wave-per-64-edge-tile. LDS transpose tile -> pre in REGISTERS
// (fixes r4 race: jb-loop previously re-read LDS positions it had overwritten).
// Fused dual GEMV (W2 + precomputed W2g) with 16 accumulators, pure reg FMA.
__global__ __launch_bounds__(256, 2) void k_edge(const float* __restrict__ u,
                                                 const float* __restrict__ v,
                                                 const int* __restrict__ esrc_srt,
                                                 const int* __restrict__ edst_srt,
                                                 const float* __restrict__ W2,
                                                 const float* __restrict__ b2,
                                                 const float* __restrict__ W2g,
                                                 const float* __restrict__ bg2,
                                                 float* __restrict__ gated) {
  __shared__ float tile[4][64 * 65];
  int w = threadIdx.x >> 6, lane = threadIdx.x & 63;
  float* T = tile[w];
  int p0 = blockIdx.x * 256 + w * 64;  // E % 256 == 0
  int s = esrc_srt[p0 + lane];
  int d = edst_srt[p0 + lane];
  // phase A: coalesced row gathers, transposed into LDS
#pragma unroll 8
  for (int i = 0; i < 64; ++i) {
    int si = __shfl(s, i, 64), di = __shfl(d, i, 64);
    float pv = u[(size_t)si * HID + lane] + v[(size_t)di * HID + lane];
    T[i * 65 + lane] = fmaxf(pv, 0.f);
  }
  // copy own row to registers (static unroll; ~64 VGPR) — T row stays intact
  float pre[HID];
#pragma unroll
  for (int k = 0; k < HID; ++k) pre[k] = T[lane * 65 + k];
  // phase B: fused dual GEMV from registers, 16 accumulators; write-back safe
#pragma unroll
  for (int jb = 0; jb < 8; ++jb) {
    float a0 = b2[jb * 8 + 0], a1 = b2[jb * 8 + 1], a2 = b2[jb * 8 + 2], a3 = b2[jb * 8 + 3];
    float a4 = b2[jb * 8 + 4], a5 = b2[jb * 8 + 5], a6 = b2[jb * 8 + 6], a7 = b2[jb * 8 + 7];
    float g0 = bg2[jb * 8 + 0], g1 = bg2[jb * 8 + 1], g2 = bg2[jb * 8 + 2], g3 = bg2[jb * 8 + 3];
    float g4 = bg2[jb * 8 + 4], g5 = bg2[jb * 8 + 5], g6 = bg2[jb * 8 + 6], g7 = bg2[jb * 8 + 7];
#pragma unroll
    for (int k = 0; k < HID; ++k) {
      float pk = pre[k];
      const float* wr = W2 + k * HID + jb * 8;
      const float* wg = W2g + k * HID + jb * 8;
      a0 += pk * wr[0]; a1 += pk * wr[1]; a2 += pk * wr[2]; a3 += pk * wr[3];
      a4 += pk * wr[4]; a5 += pk * wr[5]; a6 += pk * wr[6]; a7 += pk * wr[7];
      g0 += pk * wg[0]; g1 += pk * wg[1]; g2 += pk * wg[2]; g3 += pk * wg[3];
      g4 += pk * wg[4]; g5 += pk * wg[5]; g6 += pk * wg[6]; g7 += pk * wg[7];
    }
    T[lane * 65 + jb * 8 + 0] = a0 / (1.f + __expf(-g0));
    T[lane * 65 + jb * 8 + 1] = a1 / (1.f + __expf(-g1));
    T[lane * 65 + jb * 8 + 2] = a2 / (1.f + __expf(-g2));
    T[lane * 65 + jb * 8 + 3] = a3 / (1.f + __expf(-g3));
    T[lane * 65 + jb * 8 + 4] = a4 / (1.f + __expf(-g4));
    T[lane * 65 + jb * 8 + 5] = a5 / (1.f + __expf(-g5));
    T[lane * 65 + jb * 8 + 6] = a6 / (1.f + __expf(-g6));
    T[lane * 65 + jb * 8 + 7] = a7 / (1.f + __expf(-g7));
  }
  // phase C: coalesced contiguous store (16 KB per wave)
#pragma unroll 8
  for (int i = 0; i < 64; ++i) {
    gated[(size_t)(p0 + i) * HID + lane] = T[i * 65 + lane];
  }
}

__global__ void k_pool(const float* __restrict__ h, const float* __restrict__ gated,
                       const int* __restrict__ row_src, const int* __restrict__ deg_src,
                       const float* __restrict__ g, const float* __restrict__ b,
                       float* __restrict__ out) {
  int n = blockIdx.x * 4 + (threadIdx.x >> 6);
  int lane = threadIdx.x & 63;
  if (n >= N) return;
  int beg = row_src[n], cnt = deg_src[n];
  float acc = 0.f;
  for (int i = 0; i < cnt; ++i) acc += gated[(size_t)(beg + i) * HID + lane];
  float v = h[n * HID + lane] + acc / fmaxf((float)cnt, 1.f);
  float mu = wredsum(v) * (1.f / 64.f);
  float d = v - mu;
  float var = wredsum(d * d) * (1.f / 64.f);
  out[n * HID + lane] = d * rsqrtf(var + 1e-5f) * g[lane] + b[lane];
}

extern "C" void kernel_launch(void* const* d_in, const int* in_sizes, int n_in, void* d_out,
                              int out_size, void* d_ws, size_t ws_size, hipStream_t stream) {
  const float* x = (const float*)d_in[0];
  const int* ei = (const int*)d_in[1];
  const float* eattr = (const float*)d_in[2];
  const float* ctx = (const float*)d_in[3];
  const int* batch = (const int*)d_in[4];
  const int* role = (const int*)d_in[5];
  const int* side = (const int*)d_in[6];
  const int* form = (const int*)d_in[7];
  const int* alig = (const int*)d_in[8];
  const float* frame_t = (const float*)d_in[9];
  const float* emb_W = (const float*)d_in[10];
  const float* emb_b = (const float*)d_in[11];
  const float* role_tab = (const float*)d_in[12];
  const float* side_tab = (const float*)d_in[13];
  const float* ctx_W = (const float*)d_in[14];
  const float* ctx_b = (const float*)d_in[15];
  const float* form_tab = (const float*)d_in[16];
  const float* align_tab = (const float*)d_in[17];
  const float* temp_tab = (const float*)d_in[18];
  const float* gat_Wl = (const float*)d_in[19];
  const float* gat_bl = (const float*)d_in[20];
  const float* gat_Wr = (const float*)d_in[21];
  const float* gat_br = (const float*)d_in[22];
  const float* gat_We = (const float*)d_in[23];
  const float* gat_att = (const float*)d_in[24];
  const float* gat_bias = (const float*)d_in[25];
  const float* ln_g = (const float*)d_in[26];
  const float* ln_b = (const float*)d_in[27];
  const float* sp_W1 = (const float*)d_in[28];
  const float* sp_b1 = (const float*)d_in[29];
  const float* sp_W2 = (const float*)d_in[30];
  const float* sp_b2 = (const float*)d_in[31];
  const float* sp_Wg = (const float*)d_in[32];
  const float* sp_bg = (const float*)d_in[33];
  const float* fn_g = (const float*)d_in[34];
  const float* fn_b = (const float*)d_in[35];
  float* out = (float*)d_out;

  char* wp = (char*)d_ws;
  auto alloc = [&](size_t bytes) {
    void* p = (void*)wp;
    wp += (bytes + 255) & ~(size_t)255;
    return p;
  };
  float* h = (float*)alloc((size_t)N * HID * 4);
  float* xl = (float*)alloc((size_t)N * HH * 4);  // + xr below = 41 MB, reused as gated[E][64]
  float* xr = (float*)alloc((size_t)N * HH * 4);
  float* la = (float*)alloc((size_t)N * EDIM * 4);
  float* u = (float*)alloc((size_t)N * HID * 4);
  float* v = (float*)alloc((size_t)N * HID * 4);
  float* W2g = (float*)alloc((size_t)HID * HID * 4);
  float* bg2 = (float*)alloc((size_t)HID * 4);
  int* deg_dst = (int*)alloc((size_t)N * 4);
  int* deg_src = (int*)alloc((size_t)N * 4);
  int* row_dst = (int*)alloc((size_t)N * 4);
  int* row_src = (int*)alloc((size_t)N * 4);
  int* cur_dst = (int*)alloc((size_t)N * 4);
  int* cur_src = (int*)alloc((size_t)N * 4);
  int* eid_dst = (int*)alloc((size_t)E * 4);
  int* esrc_dst = (int*)alloc((size_t)E * 4);
  int* esrc_srt = (int*)alloc((size_t)E * 4);
  int* edst_srt = (int*)alloc((size_t)E * 4);
  float* gated = xl;  // [E][64] = 41 MB, spans xl+xr (both dead by then)

  hipMemsetAsync(deg_dst, 0, (size_t)N * 4, stream);
  hipMemsetAsync(deg_src, 0, (size_t)N * 4, stream);

  k_node_init<<<(N * HID + 255) / 256, 256, 0, stream>>>(
      x, emb_W, emb_b, role, role_tab, side, side_tab, frame_t, temp_tab, batch, ctx, ctx_W,
      ctx_b, form_tab, align_tab, form, alig, h);
  k_count<<<(E + 255) / 256, 256, 0, stream>>>(ei, deg_dst, deg_src);
  k_fuse<<<16, 256, 0, stream>>>(sp_W2, sp_Wg, sp_b2, sp_bg, W2g, bg2);
  k_scan2<<<1, 1024, 0, stream>>>(deg_dst, row_dst, cur_dst, deg_src, row_src, cur_src, N);
  k_scatter<<<(E + 255) / 256, 256, 0, stream>>>(ei, cur_dst, cur_src, eid_dst, esrc_dst,
                                                 esrc_srt, edst_srt);
  k_loop_attr<<<(N + 255) / 256, 256, 0, stream>>>(row_dst, deg_dst, eid_dst, eattr, la);

  for (int i = 0; i < NL; ++i) {
    k_xlxr<<<(N + 15) / 16, 256, 0, stream>>>(h, gat_Wl + (size_t)i * HID * HH, gat_bl + i * HH,
                                              gat_Wr + (size_t)i * HID * HH, gat_br + i * HH, xl,
                                              xr);
    k_gat<<<N, 256, 0, stream>>>(xl, xr, eattr, la, row_dst, deg_dst, eid_dst, esrc_dst,
                                 gat_We + (size_t)i * EDIM * HH, gat_att + i * HH,
                                 gat_bias + i * HID, ln_g + i * HID, ln_b + i * HID, h);
  }

  k_uv<<<(N + 15) / 16, 256, 0, stream>>>(h, sp_W1, sp_b1, u, v);
  k_edge<<<E / 256, 256, 0, stream>>>(u, v, esrc_srt, edst_srt, sp_W2, sp_b2, W2g, bg2, gated);
  k_pool<<<(N + 3) / 4, 256, 0, stream>>>(h, gated, row_src, deg_src, fn_g, fn_b, out);
}

// Round 6
// 854.881 us; speedup vs baseline: 1.3503x; 1.3503x over previous
//
#include <hip/hip_runtime.h>
#include <math.h>

constexpr int N = 20000, E = 160000, Bb = 1000;
constexpr int DIN = 7, HID = 64, HEADS = 4, CTXD = 3, EDIM = 5, NL = 4;
constexpr int HH = HEADS * HID; // 256

__device__ __forceinline__ float wredsum(float v) {
#pragma unroll
  for (int o = 32; o; o >>= 1) v += __shfl_xor(v, o, 64);
  return v;
}

__device__ __forceinline__ float wredmax(float v) {
#pragma unroll
  for (int o = 32; o; o >>= 1) v = fmaxf(v, __shfl_xor(v, o, 64));
  return v;
}

// node init with ctx MLP fused in (3 FMAs per thread, saves a kernel+buffer)
__global__ void k_node_init(const float* __restrict__ x, const float* __restrict__ emb_W,
                            const float* __restrict__ emb_b, const int* __restrict__ role,
                            const float* __restrict__ role_tab, const int* __restrict__ side,
                            const float* __restrict__ side_tab, const float* __restrict__ frame_t,
                            const float* __restrict__ temp_tab, const int* __restrict__ batch,
                            const float* __restrict__ ctx, const float* __restrict__ ctx_W,
                            const float* __restrict__ ctx_b, const float* __restrict__ form_tab,
                            const float* __restrict__ align_tab, const int* __restrict__ form,
                            const int* __restrict__ alig, float* __restrict__ h) {
  int t = blockIdx.x * blockDim.x + threadIdx.x;
  if (t >= N * HID) return;
  int n = t >> 6, j = t & 63;
  float a = emb_b[j];
#pragma unroll
  for (int k = 0; k < DIN; ++k) a += x[n * DIN + k] * emb_W[k * HID + j];
  a = fmaxf(a, 0.f);
  a += role_tab[role[n] * HID + j];
  if (j < 32) a += side_tab[side[n] * 32 + j];
  int ti = (int)(frame_t[0] * 99.f);
  ti = ti < 0 ? 0 : (ti > 99 ? 99 : ti);
  a += temp_tab[ti * HID + j];
  int b = batch[n];
  float c = ctx_b[j];
#pragma unroll
  for (int k = 0; k < CTXD; ++k) c += ctx[b * CTXD + k] * ctx_W[k * HID + j];
  c = fmaxf(c, 0.f);
  c += form_tab[form[b] * HID + j] + align_tab[alig[b] * HID + j];
  h[t] = a + c;
}

__global__ void k_count(const int* __restrict__ ei, int* __restrict__ deg_dst,
                        int* __restrict__ deg_src) {
  int e = blockIdx.x * blockDim.x + threadIdx.x;
  if (e >= E) return;
  atomicAdd(&deg_src[ei[e]], 1);
  atomicAdd(&deg_dst[ei[E + e]], 1);
}

// W2g = W2 @ Wg ; bg2 = bg + b2 @ Wg   (lets k_edge compute gate from pre directly)
__global__ void k_fuse(const float* __restrict__ W2, const float* __restrict__ Wg,
                       const float* __restrict__ b2, const float* __restrict__ bg,
                       float* __restrict__ W2g, float* __restrict__ bg2) {
  int t = blockIdx.x * 256 + threadIdx.x;
  if (t < HID * HID) {
    int i = t >> 6, j = t & 63;
    float a = 0.f;
#pragma unroll
    for (int k = 0; k < HID; ++k) a += W2[i * HID + k] * Wg[k * HID + j];
    W2g[t] = a;
  }
  if (t < HID) {
    float a = bg[t];
#pragma unroll
    for (int k = 0; k < HID; ++k) a += b2[k] * Wg[k * HID + t];
    bg2[t] = a;
  }
}

// both exclusive scans in one launch; shfl wave-scan + cross-wave LDS
__global__ void k_scan2(const int* __restrict__ degA, int* __restrict__ rowA,
                        int* __restrict__ curA, const int* __restrict__ degB,
                        int* __restrict__ rowB, int* __restrict__ curB, int n) {
  __shared__ int wsum[16];
  __shared__ int carry;
  int t = threadIdx.x, wid = t >> 6, lane = t & 63;
  for (int pass = 0; pass < 2; ++pass) {
    const int* deg = pass ? degB : degA;
    int* row = pass ? rowB : rowA;
    int* cur = pass ? curB : curA;
    if (t == 0) carry = 0;
    __syncthreads();
    for (int base = 0; base < n; base += 1024) {
      int v = (base + t < n) ? deg[base + t] : 0;
      int s = v;
#pragma unroll
      for (int off = 1; off < 64; off <<= 1) {
        int x = __shfl_up(s, off, 64);
        if (lane >= off) s += x;
      }
      if (lane == 63) wsum[wid] = s;
      __syncthreads();
      if (wid == 0) {
        int ws = (lane < 16) ? wsum[lane] : 0;
#pragma unroll
        for (int off = 1; off < 16; off <<= 1) {
          int x = __shfl_up(ws, off, 64);
          if (lane >= off) ws += x;
        }
        if (lane < 16) wsum[lane] = ws;
      }
      __syncthreads();
      int wexcl = (wid == 0) ? 0 : wsum[wid - 1];
      int r = carry + wexcl + (s - v);
      if (base + t < n) {
        row[base + t] = r;
        cur[base + t] = r;
      }
      __syncthreads();
      if (t == 0) carry += wsum[15];
      __syncthreads();
    }
  }
}

__global__ void k_scatter(const int* __restrict__ ei, int* __restrict__ cur_dst,
                          int* __restrict__ cur_src, int* __restrict__ eid_dst,
                          int* __restrict__ esrc_dst, int* __restrict__ esrc_srt,
                          int* __restrict__ edst_srt) {
  int e = blockIdx.x * blockDim.x + threadIdx.x;
  if (e >= E) return;
  int s = ei[e], d = ei[E + e];
  int ps = atomicAdd(&cur_src[s], 1);
  esrc_srt[ps] = s;
  edst_srt[ps] = d;
  int pd = atomicAdd(&cur_dst[d], 1);
  eid_dst[pd] = e;
  esrc_dst[pd] = s;
}

__global__ void k_loop_attr(const int* __restrict__ row_dst, const int* __restrict__ deg_dst,
                            const int* __restrict__ eid_dst, const float* __restrict__ ea,
                            float* __restrict__ la) {
  int n = blockIdx.x * blockDim.x + threadIdx.x;
  if (n >= N) return;
  int beg = row_dst[n], cnt = deg_dst[n];
  float s[EDIM] = {0.f, 0.f, 0.f, 0.f, 0.f};
  for (int j = 0; j < cnt; ++j) {
    int e = eid_dst[beg + j];
#pragma unroll
    for (int k = 0; k < EDIM; ++k) s[k] += ea[(size_t)e * EDIM + k];
  }
  float inv = 1.f / fmaxf((float)cnt, 1.f);
#pragma unroll
  for (int k = 0; k < EDIM; ++k) la[n * EDIM + k] = s[k] * inv;
}

__global__ __launch_bounds__(256) void k_xlxr(const float* __restrict__ h,
                                              const float* __restrict__ Wl,
                                              const float* __restrict__ bl,
                                              const float* __restrict__ Wr,
                                              const float* __restrict__ br,
                                              float* __restrict__ xl, float* __restrict__ xr) {
  constexpr int NB = 16;
  __shared__ float hs[NB][HID];
  int n0 = blockIdx.x * NB;
  for (int idx = threadIdx.x; idx < NB * HID; idx += 256) {
    int r = idx >> 6, c = idx & 63;
    int n = n0 + r;
    hs[r][c] = (n < N) ? h[n * HID + c] : 0.f;
  }
  __syncthreads();
  int t = threadIdx.x;
  float wl[HID], wr[HID];
#pragma unroll
  for (int k = 0; k < HID; ++k) {
    wl[k] = Wl[k * HH + t];
    wr[k] = Wr[k * HH + t];
  }
  float blv = bl[t], brv = br[t];
  for (int r = 0; r < NB; ++r) {
    int n = n0 + r;
    if (n >= N) break;
    float al = blv, ar = brv;
#pragma unroll
    for (int k = 0; k < HID; ++k) {
      float hv = hs[r][k];
      al += hv * wl[k];
      ar += hv * wr[k];
    }
    xl[(size_t)n * HH + t] = al;
    xr[(size_t)n * HH + t] = ar;
  }
}

// per-node GATv2. Logit phase: 16-lane groups, 4 edges/wave/iter, float4 cols,
// 4-step group reduce -> LDS. Then wave max/exp/sum, then pure-FMA accumulate.
__global__ __launch_bounds__(256) void k_gat(
    const float* __restrict__ xl, const float* __restrict__ xr, const float* __restrict__ ea,
    const float* __restrict__ la, const int* __restrict__ row_dst,
    const int* __restrict__ deg_dst, const int* __restrict__ eid_dst,
    const int* __restrict__ esrc_dst, const float* __restrict__ We,
    const float* __restrict__ att, const float* __restrict__ biasL,
    const float* __restrict__ lng, const float* __restrict__ lnb, float* __restrict__ h) {
  int n = blockIdx.x;
  int w = threadIdx.x >> 6, lane = threadIdx.x & 63;
  int col = w * HID + lane;
  int g = lane >> 4, q = lane & 15, c4 = q * 4;
  const float* base = xr + (size_t)n * HH + w * HID + c4;
  float4 xr4 = *(const float4*)base;
  float4 att4 = *(const float4*)(att + w * HID + c4);
  float4 we4[EDIM];
#pragma unroll
  for (int k = 0; k < EDIM; ++k) we4[k] = *(const float4*)(We + k * HH + w * HID + c4);
  int beg = row_dst[n], cnt = deg_dst[n];
  int tot = cnt + 1;  // + self loop (idx 0)
  int ncache = cnt < 63 ? cnt : 63;
  int srcn_c = (lane < ncache) ? esrc_dst[beg + lane] : 0;
  int eid_c = (lane < ncache) ? eid_dst[beg + lane] : 0;
  int nf = tot < 64 ? tot : 64;
  __shared__ float lgs[HEADS][64];
  for (int j = 0; j * 4 < nf; ++j) {
    int idx = j * 4 + g;
    float dot = 0.f;
    if (idx < nf) {
      int srcn = (idx == 0) ? n : __shfl(srcn_c, idx - 1, 64);
      const float* eap;
      if (idx == 0) {
        eap = la + (size_t)n * EDIM;
      } else {
        int e = __shfl(eid_c, idx - 1, 64);
        eap = ea + (size_t)e * EDIM;
      }
      float4 ep;
      ep.x = ep.y = ep.z = ep.w = 0.f;
#pragma unroll
      for (int k = 0; k < EDIM; ++k) {
        float ev = eap[k];
        ep.x += ev * we4[k].x;
        ep.y += ev * we4[k].y;
        ep.z += ev * we4[k].z;
        ep.w += ev * we4[k].w;
      }
      float4 xl4 = *(const float4*)(xl + (size_t)srcn * HH + w * HID + c4);
      float v0 = xl4.x + xr4.x + ep.x;
      float v1 = xl4.y + xr4.y + ep.y;
      float v2 = xl4.z + xr4.z + ep.z;
      float v3 = xl4.w + xr4.w + ep.w;
      v0 = v0 > 0.f ? v0 : 0.2f * v0;
      v1 = v1 > 0.f ? v1 : 0.2f * v1;
      v2 = v2 > 0.f ? v2 : 0.2f * v2;
      v3 = v3 > 0.f ? v3 : 0.2f * v3;
      dot = v0 * att4.x + v1 * att4.y + v2 * att4.z + v3 * att4.w;
    }
#pragma unroll
    for (int o = 1; o < 16; o <<= 1) dot += __shfl_xor(dot, o, 64);
    if (q == 0 && idx < nf) lgs[w][idx] = dot;
  }
  float mylg = (lane < nf) ? lgs[w][lane] : -INFINITY;
  float m = wredmax(mylg);
  float p = (lane < nf) ? __expf(mylg - m) : 0.f;
  float s = wredsum(p);
  float acc = 0.f;
  for (int idx = 0; idx < nf; ++idx) {
    int srcn = (idx == 0) ? n : __shfl(srcn_c, idx - 1, 64);
    float pi = __shfl(p, idx, 64);
    acc += pi * xl[(size_t)srcn * HH + col];
  }
  // overflow (deg > 63), rare: online merge with lazily-loaded scalar We col
  if (tot > 64) {
    float wes[EDIM];
#pragma unroll
    for (int k = 0; k < EDIM; ++k) wes[k] = We[k * HH + col];
    float xrs = xr[(size_t)n * HH + col];
    float attws = att[col];
    for (int idx = 64; idx < tot; ++idx) {
      int pos = beg + idx - 1;
      int srcn = esrc_dst[pos];
      int e = eid_dst[pos];
      const float* eap = ea + (size_t)e * EDIM;
      float ep = 0.f;
#pragma unroll
      for (int k = 0; k < EDIM; ++k) ep += eap[k] * wes[k];
      float xls = xl[(size_t)srcn * HH + col];
      float v = xls + xrs + ep;
      v = v > 0.f ? v : 0.2f * v;
      float lg = wredsum(v * attws);
      float nm = fmaxf(m, lg);
      float sc = __expf(m - nm), pp = __expf(lg - nm);
      s = s * sc + pp;
      acc = acc * sc + pp * xls;
      m = nm;
    }
  }
  float outv = acc / (s + 1e-16f);
  __shared__ float heads[HEADS][HID];
  heads[w][lane] = outv;
  __syncthreads();
  if (w == 0) {
    float hv = (heads[0][lane] + heads[1][lane] + heads[2][lane] + heads[3][lane]) * 0.25f +
               biasL[lane];
    hv = fmaxf(hv, 0.f);
    float v = hv + h[n * HID + lane];
    float mu = wredsum(v) * (1.f / 64.f);
    float d = v - mu;
    float var = wredsum(d * d) * (1.f / 64.f);
    h[n * HID + lane] = d * rsqrtf(var + 1e-5f) * lng[lane] + lnb[lane];
  }
}

__global__ __launch_bounds__(256) void k_uv(const float* __restrict__ h,
                                            const float* __restrict__ W1,
                                            const float* __restrict__ b1,
                                            float* __restrict__ u, float* __restrict__ v) {
  constexpr int NB = 16;
  __shared__ float hs[NB][HID];
  int n0 = blockIdx.x * NB;
  for (int idx = threadIdx.x; idx < NB * HID; idx += 256) {
    int r = idx >> 6, c = idx & 63;
    int n = n0 + r;
    hs[r][c] = (n < N) ? h[n * HID + c] : 0.f;
  }
  __syncthreads();
  int j = threadIdx.x & 63, q = threadIdx.x >> 6;
  float wa[HID], wb[HID];
#pragma unroll
  for (int k = 0; k < HID; ++k) {
    wa[k] = W1[k * HID + j];
    wb[k] = W1[(HID + k) * HID + j];
  }
  float b1v = b1[j];
  for (int r = q; r < NB; r += 4) {
    int n = n0 + r;
    if (n >= N) continue;
    float au = b1v, av = 0.f;
#pragma unroll
    for (int k = 0; k < HID; ++k) {
      float hv = hs[r][k];
      au += hv * wa[k];
      av += hv * wb[k];
    }
    u[(size_t)n * HID + j] = au;
    v[(size_t)n * HID + j] = av;
  }
}

// v6: lane = output feature. W2/W2g columns live in 128 VGPRs per lane;
// per edge one coalesced activation row read, readlane-broadcast GEMV,
// zero LDS, zero inner-loop memory ops, coalesced row store.
__global__ __launch_bounds__(256, 2) void k_edge(const float* __restrict__ u,
                                                 const float* __restrict__ v,
                                                 const int* __restrict__ esrc_srt,
                                                 const int* __restrict__ edst_srt,
                                                 const float* __restrict__ W2,
                                                 const float* __restrict__ b2,
                                                 const float* __restrict__ W2g,
                                                 const float* __restrict__ bg2,
                                                 float* __restrict__ gated) {
  int w = threadIdx.x >> 6, lane = threadIdx.x & 63;
  int t0 = blockIdx.x * 256 + w * 64;  // E % 256 == 0
  float w2c[HID], wgc[HID];
#pragma unroll
  for (int k = 0; k < HID; ++k) {
    w2c[k] = W2[k * HID + lane];   // coalesced: consecutive lanes, consecutive floats
    wgc[k] = W2g[k * HID + lane];
  }
  float b2v = b2[lane], bgv = bg2[lane];
  int sv = esrc_srt[t0 + lane];
  int dv = edst_srt[t0 + lane];
#pragma unroll 1
  for (int i = 0; i < 64; i += 2) {
    int s0 = __shfl(sv, i, 64), d0 = __shfl(dv, i, 64);
    int s1 = __shfl(sv, i + 1, 64), d1 = __shfl(dv, i + 1, 64);
    float p0 = fmaxf(u[(size_t)s0 * HID + lane] + v[(size_t)d0 * HID + lane], 0.f);
    float p1 = fmaxf(u[(size_t)s1 * HID + lane] + v[(size_t)d1 * HID + lane], 0.f);
    // 8 independent FMA chains (2 edges x {it,gt} x 2 k-halves)
    float itA0 = b2v, gtA0 = bgv, itA1 = b2v, gtA1 = bgv;
    float itB0 = 0.f, gtB0 = 0.f, itB1 = 0.f, gtB1 = 0.f;
#pragma unroll
    for (int k = 0; k < 32; ++k) {
      float a0 = __shfl(p0, k, 64);
      float b0 = __shfl(p0, k + 32, 64);
      float a1 = __shfl(p1, k, 64);
      float b1x = __shfl(p1, k + 32, 64);
      itA0 += a0 * w2c[k];      gtA0 += a0 * wgc[k];
      itB0 += b0 * w2c[k + 32]; gtB0 += b0 * wgc[k + 32];
      itA1 += a1 * w2c[k];      gtA1 += a1 * wgc[k];
      itB1 += b1x * w2c[k + 32]; gtB1 += b1x * wgc[k + 32];
    }
    float it0 = itA0 + itB0, gt0 = gtA0 + gtB0;
    float it1 = itA1 + itB1, gt1 = gtA1 + gtB1;
    gated[(size_t)(t0 + i) * HID + lane] = it0 / (1.f + __expf(-gt0));
    gated[(size_t)(t0 + i + 1) * HID + lane] = it1 / (1.f + __expf(-gt1));
  }
}

__global__ void k_pool(const float* __restrict__ h, const float* __restrict__ gated,
                       const int* __restrict__ row_src, const int* __restrict__ deg_src,
                       const float* __restrict__ g, const float* __restrict__ b,
                       float* __restrict__ out) {
  int n = blockIdx.x * 4 + (threadIdx.x >> 6);
  int lane = threadIdx.x & 63;
  if (n >= N) return;
  int beg = row_src[n], cnt = deg_src[n];
  float acc = 0.f;
  for (int i = 0; i < cnt; ++i) acc += gated[(size_t)(beg + i) * HID + lane];
  float v = h[n * HID + lane] + acc / fmaxf((float)cnt, 1.f);
  float mu = wredsum(v) * (1.f / 64.f);
  float d = v - mu;
  float var = wredsum(d * d) * (1.f / 64.f);
  out[n * HID + lane] = d * rsqrtf(var + 1e-5f) * g[lane] + b[lane];
}

extern "C" void kernel_launch(void* const* d_in, const int* in_sizes, int n_in, void* d_out,
                              int out_size, void* d_ws, size_t ws_size, hipStream_t stream) {
  const float* x = (const float*)d_in[0];
  const int* ei = (const int*)d_in[1];
  const float* eattr = (const float*)d_in[2];
  const float* ctx = (const float*)d_in[3];
  const int* batch = (const int*)d_in[4];
  const int* role = (const int*)d_in[5];
  const int* side = (const int*)d_in[6];
  const int* form = (const int*)d_in[7];
  const int* alig = (const int*)d_in[8];
  const float* frame_t = (const float*)d_in[9];
  const float* emb_W = (const float*)d_in[10];
  const float* emb_b = (const float*)d_in[11];
  const float* role_tab = (const float*)d_in[12];
  const float* side_tab = (const float*)d_in[13];
  const float* ctx_W = (const float*)d_in[14];
  const float* ctx_b = (const float*)d_in[15];
  const float* form_tab = (const float*)d_in[16];
  const float* align_tab = (const float*)d_in[17];
  const float* temp_tab = (const float*)d_in[18];
  const float* gat_Wl = (const float*)d_in[19];
  const float* gat_bl = (const float*)d_in[20];
  const float* gat_Wr = (const float*)d_in[21];
  const float* gat_br = (const float*)d_in[22];
  const float* gat_We = (const float*)d_in[23];
  const float* gat_att = (const float*)d_in[24];
  const float* gat_bias = (const float*)d_in[25];
  const float* ln_g = (const float*)d_in[26];
  const float* ln_b = (const float*)d_in[27];
  const float* sp_W1 = (const float*)d_in[28];
  const float* sp_b1 = (const float*)d_in[29];
  const float* sp_W2 = (const float*)d_in[30];
  const float* sp_b2 = (const float*)d_in[31];
  const float* sp_Wg = (const float*)d_in[32];
  const float* sp_bg = (const float*)d_in[33];
  const float* fn_g = (const float*)d_in[34];
  const float* fn_b = (const float*)d_in[35];
  float* out = (float*)d_out;

  char* wp = (char*)d_ws;
  auto alloc = [&](size_t bytes) {
    void* p = (void*)wp;
    wp += (bytes + 255) & ~(size_t)255;
    return p;
  };
  float* h = (float*)alloc((size_t)N * HID * 4);
  float* xl = (float*)alloc((size_t)N * HH * 4);  // + xr below = 41 MB, reused as gated[E][64]
  float* xr = (float*)alloc((size_t)N * HH * 4);
  float* la = (float*)alloc((size_t)N * EDIM * 4);
  float* u = (float*)alloc((size_t)N * HID * 4);
  float* v = (float*)alloc((size_t)N * HID * 4);
  float* W2g = (float*)alloc((size_t)HID * HID * 4);
  float* bg2 = (float*)alloc((size_t)HID * 4);
  int* deg_dst = (int*)alloc((size_t)N * 4);
  int* deg_src = (int*)alloc((size_t)N * 4);
  int* row_dst = (int*)alloc((size_t)N * 4);
  int* row_src = (int*)alloc((size_t)N * 4);
  int* cur_dst = (int*)alloc((size_t)N * 4);
  int* cur_src = (int*)alloc((size_t)N * 4);
  int* eid_dst = (int*)alloc((size_t)E * 4);
  int* esrc_dst = (int*)alloc((size_t)E * 4);
  int* esrc_srt = (int*)alloc((size_t)E * 4);
  int* edst_srt = (int*)alloc((size_t)E * 4);
  float* gated = xl;  // [E][64] = 41 MB, spans xl+xr (both dead by then)

  hipMemsetAsync(deg_dst, 0, (size_t)N * 4, stream);
  hipMemsetAsync(deg_src, 0, (size_t)N * 4, stream);

  k_node_init<<<(N * HID + 255) / 256, 256, 0, stream>>>(
      x, emb_W, emb_b, role, role_tab, side, side_tab, frame_t, temp_tab, batch, ctx, ctx_W,
      ctx_b, form_tab, align_tab, form, alig, h);
  k_count<<<(E + 255) / 256, 256, 0, stream>>>(ei, deg_dst, deg_src);
  k_fuse<<<16, 256, 0, stream>>>(sp_W2, sp_Wg, sp_b2, sp_bg, W2g, bg2);
  k_scan2<<<1, 1024, 0, stream>>>(deg_dst, row_dst, cur_dst, deg_src, row_src, cur_src, N);
  k_scatter<<<(E + 255) / 256, 256, 0, stream>>>(ei, cur_dst, cur_src, eid_dst, esrc_dst,
                                                 esrc_srt, edst_srt);
  k_loop_attr<<<(N + 255) / 256, 256, 0, stream>>>(row_dst, deg_dst, eid_dst, eattr, la);

  for (int i = 0; i < NL; ++i) {
    k_xlxr<<<(N + 15) / 16, 256, 0, stream>>>(h, gat_Wl + (size_t)i * HID * HH, gat_bl + i * HH,
                                              gat_Wr + (size_t)i * HID * HH, gat_br + i * HH, xl,
                                              xr);
    k_gat<<<N, 256, 0, stream>>>(xl, xr, eattr, la, row_dst, deg_dst, eid_dst, esrc_dst,
                                 gat_We + (size_t)i * EDIM * HH, gat_att + i * HH,
                                 gat_bias + i * HID, ln_g + i * HID, ln_b + i * HID, h);
  }

  k_uv<<<(N + 15) / 16, 256, 0, stream>>>(h, sp_W1, sp_b1, u, v);
  k_edge<<<E / 256, 256, 0, stream>>>(u, v, esrc_srt, edst_srt, sp_W2, sp_b2, W2g, bg2, gated);
  k_pool<<<(N + 3) / 4, 256, 0, stream>>>(h, gated, row_src, deg_src, fn_g, fn_b, out);
}